// Round 2
// baseline (4915.593 us; speedup 1.0000x reference)
//
#include <hip/hip_runtime.h>
#include <hip/hip_bf16.h>
#include <stdint.h>
#include <stddef.h>

// ---------------------------------------------------------------------------
// Seq2Seq BiGRU: B=256 T=512 F=64 H=256 (2-layer bidir encoder),
// decoder DH=512 2-layer, OSL=20, OUT=2.
//
// Round-2 structure (crash fixes: ws_size-adaptive chunking, LDS < 64 KiB):
//  - gemm_gi: gi chunk [Tc][B][1536] bf16 = input@Wih^T, bwd dir stored
//    time-reversed so both directions consume rows in scan order.
//  - gru_scan (chunked): 32 WGs (dir x 16 batch rows), Whh register-resident
//    as MFMA B-frags, fp32 h carry in registers, bf16 h in LDS for A-frags.
//    h state persists between chunk launches in global hstate.
//  - decoder: Weff = dec_Wih0 @ fcW folded (all-linear chain), 2x20 dec_cell
//    launches + fc_all.
// ---------------------------------------------------------------------------

typedef __bf16 bf16_t;
typedef bf16_t bf16x8 __attribute__((ext_vector_type(8)));
typedef float  f32x4  __attribute__((ext_vector_type(4)));

#define B_   256
#define T_   512
#define F_   64
#define H_   256
#define G_   768      // 3*H
#define DH_  512
#define DG_  1536     // 3*DH
#define OSL_ 20

__device__ __forceinline__ float sigm(float x) {
    float e = __builtin_amdgcn_exp2f(-1.442695040888963f * x);
    return __builtin_amdgcn_rcpf(1.0f + e);
}
__device__ __forceinline__ float tanh_(float x) {
    float e = __builtin_amdgcn_exp2f(-2.885390081777927f * x);
    return __builtin_amdgcn_rcpf(1.0f + e) * 2.0f - 1.0f;
}

__device__ __forceinline__ bf16x8 load_f32x8_as_bf16(const float* p) {
    f32x4 u = *(const f32x4*)p;
    f32x4 v = *(const f32x4*)(p + 4);
    bf16x8 r;
    r[0]=(bf16_t)u[0]; r[1]=(bf16_t)u[1]; r[2]=(bf16_t)u[2]; r[3]=(bf16_t)u[3];
    r[4]=(bf16_t)v[0]; r[5]=(bf16_t)v[1]; r[6]=(bf16_t)v[2]; r[7]=(bf16_t)v[3];
    return r;
}

// ------------------------------- prep kernels ------------------------------

__global__ void cast_f32_bf16(const float* __restrict__ src, bf16_t* __restrict__ dst, int n) {
    int i = blockIdx.x * 256 + threadIdx.x;
    if (i < n) dst[i] = (bf16_t)src[i];
}

// Weff[g][k] = dec_Wih0[g][:]@fcW[:][k]; beff = dec_Wih0@fc_b + dec_bih0;
// ov = dec_Wih0@start_token + dec_bih0  (step-0 gi, constant across batch)
__global__ void weff_prep(const float* __restrict__ wih0d, const float* __restrict__ fcw,
                          const float* __restrict__ fcb, const float* __restrict__ bih0d,
                          const float* __restrict__ st, bf16_t* __restrict__ weff,
                          float* __restrict__ beff, float* __restrict__ ov) {
    int tid = blockIdx.x * 256 + threadIdx.x;
    if (tid >= DG_ * DH_) return;
    int g = tid >> 9, k = tid & 511;
    float a0 = wih0d[g * 2], a1 = wih0d[g * 2 + 1];
    weff[tid] = (bf16_t)(a0 * fcw[k] + a1 * fcw[DH_ + k]);
    if (k == 0) {
        beff[g] = a0 * fcb[0] + a1 * fcb[1] + bih0d[g];
        ov[g]   = a0 * st[0]  + a1 * st[1]  + bih0d[g];
    }
}

// --------------------------- gi chunk GEMM ---------------------------------
// gi[r][n] (r = tl*256+b local to chunk, n in [0,1536)) =
//   A_time(t_real)[b] @ Wih[n]^T,  t_real = t0+tl for n<768 (fwd),
//                                  511-(t0+tl) for n>=768 (bwd, time-reversed).
// K==64: A = x f32 [B][T][64]; else K==512: A = xcat bf16 [T][B][512].
__global__ __launch_bounds__(256) void gemm_gi(
    const float* __restrict__ x, const bf16_t* __restrict__ xcat,
    const bf16_t* __restrict__ Bt, bf16_t* __restrict__ gi, int t0, int K) {
    __shared__ bf16_t As[128 * 64];
    __shared__ bf16_t Bs[128 * 64];
    int m0 = blockIdx.x * 128, n0 = blockIdx.y * 128;
    int tid = threadIdx.x;
    int lane = tid & 63, w = tid >> 6;
    int col = lane & 15, quad = lane >> 4;
    int qm = (w >> 1) * 64, qn = (w & 1) * 64;

    int tl = m0 >> 8;              // local chunk time (constant per block)
    int bbase = m0 & 255;          // batch base (0 or 128)
    int t_real = t0 + tl;
    if (n0 >= 768) t_real = (T_ - 1) - t_real;

    f32x4 acc[4][4] = {};
    for (int k0 = 0; k0 < K; k0 += 64) {
        __syncthreads();
#pragma unroll
        for (int i = 0; i < 4; i++) {
            int c = i * 256 + tid;
            int m = c >> 3, kc = c & 7;
            int kcs = kc ^ (m & 7);   // XOR swizzle at source
            bf16x8 av;
            if (K == 64) {
                av = load_f32x8_as_bf16(x + ((size_t)(bbase + m) * T_ + t_real) * F_ + kcs * 8);
            } else {
                av = *(const bf16x8*)(xcat + ((size_t)t_real * B_ + bbase + m) * DH_ + k0 + kcs * 8);
            }
            *(bf16x8*)(&As[c * 8]) = av;
            *(bf16x8*)(&Bs[c * 8]) = *(const bf16x8*)(Bt + (size_t)(n0 + m) * K + k0 + kcs * 8);
        }
        __syncthreads();
#pragma unroll
        for (int kt = 0; kt < 2; kt++) {
            bf16x8 a[4], b[4];
#pragma unroll
            for (int mt = 0; mt < 4; mt++) {
                int r = qm + mt * 16 + col;
                a[mt] = *(const bf16x8*)(&As[(r * 8 + ((kt * 4 + quad) ^ (r & 7))) * 8]);
                int rn = qn + mt * 16 + col;
                b[mt] = *(const bf16x8*)(&Bs[(rn * 8 + ((kt * 4 + quad) ^ (rn & 7))) * 8]);
            }
#pragma unroll
            for (int mt = 0; mt < 4; mt++)
#pragma unroll
                for (int nt = 0; nt < 4; nt++)
                    acc[mt][nt] = __builtin_amdgcn_mfma_f32_16x16x32_bf16(a[mt], b[nt], acc[mt][nt], 0, 0, 0);
        }
    }
#pragma unroll
    for (int mt = 0; mt < 4; mt++)
#pragma unroll
        for (int nt = 0; nt < 4; nt++)
#pragma unroll
            for (int i = 0; i < 4; i++) {
                int row = m0 + qm + mt * 16 + quad * 4 + i;
                int cg  = n0 + qn + nt * 16 + col;
                gi[(size_t)row * DG_ + cg] = (bf16_t)acc[mt][nt][i];
            }
}

// ------------------------------ GRU scan (chunked) -------------------------
// One WG = 512 thr = 8 waves handles (direction, 16 batch rows) for steps
// [t0, t0+tc). Whh (768x256 bf16) register-resident as MFMA B-frags: wave w
// owns hidden units j in [w*32, w*32+32) i.e. gate rows {j, 256+j, 512+j}.
// fp32 h carry lives in per-lane registers (each lane owns 8 fixed (b,j)).
// gi chunk rows are already in scan order for both dirs (bwd stored reversed).
// LDS: gi single buffer 24 KiB + h double buffer 16.5 KiB = 41 KiB (< 64 KiB).
__global__ __launch_bounds__(512) void gru_scan(
    const bf16_t* __restrict__ gi, int t0, int tc,
    const bf16_t* __restrict__ whh,
    const float* __restrict__ bih, const float* __restrict__ bhh,
    float* __restrict__ hstate, bf16_t* __restrict__ y, float* __restrict__ hT) {
    __shared__ bf16_t gi_lds[16 * 768];       // [b][768]
    __shared__ bf16_t h_lds[2 * 16 * 264];    // [par][b][256+8 pad]

    int dir = blockIdx.x >> 4;
    int b0  = (blockIdx.x & 15) * 16;
    int tid = threadIdx.x;
    int w = tid >> 6, lane = tid & 63, col = lane & 15, quad = lane >> 4;

    // resident recurrent weights
    bf16x8 wf[3][2][8];
    const bf16_t* wbase = whh + (size_t)dir * G_ * H_;
#pragma unroll
    for (int g = 0; g < 3; g++)
#pragma unroll
        for (int nt = 0; nt < 2; nt++) {
            int row = g * 256 + w * 32 + nt * 16 + col;
#pragma unroll
            for (int kt = 0; kt < 8; kt++)
                wf[g][nt][kt] = *(const bf16x8*)(wbase + (size_t)row * H_ + kt * 32 + quad * 8);
        }
    // biases
    float brz[2][2], bin_[2], bhn[2];
#pragma unroll
    for (int nt = 0; nt < 2; nt++) {
        int j = w * 32 + nt * 16 + col;
        brz[0][nt] = bih[dir * G_ + j] + bhh[dir * G_ + j];
        brz[1][nt] = bih[dir * G_ + 256 + j] + bhh[dir * G_ + 256 + j];
        bin_[nt]   = bih[dir * G_ + 512 + j];
        bhn[nt]    = bhh[dir * G_ + 512 + j];
    }
    // gi staging map: 1536 chunks of 8 bf16 cover [16][768]
    int bb[3], oo[3];
#pragma unroll
    for (int it = 0; it < 3; it++) {
        int c = it * 512 + tid;
        bb[it] = c / 96;
        oo[it] = (c % 96) * 8;
    }
    // init h (zero at t0==0 else from hstate), fp32 carry in registers
    float hold[2][4];
#pragma unroll
    for (int nt = 0; nt < 2; nt++)
#pragma unroll
        for (int i = 0; i < 4; i++) {
            int j = w * 32 + nt * 16 + col;
            hold[nt][i] = t0 ? hstate[dir * 65536 + (b0 + quad * 4 + i) * 256 + j] : 0.0f;
        }
    for (int i = tid; i < 16 * 264; i += 512) {
        int b = i / 264, j = i % 264;
        float v = (t0 && j < 256) ? hstate[dir * 65536 + (b0 + b) * 256 + j] : 0.0f;
        h_lds[i] = (bf16_t)v;
    }
    // stage gi row 0
#pragma unroll
    for (int it = 0; it < 3; it++) {
        int c = it * 512 + tid;
        *(bf16x8*)(&gi_lds[c * 8]) =
            *(const bf16x8*)(gi + ((size_t)0 * B_ + b0 + bb[it]) * DG_ + dir * G_ + oo[it]);
    }
    __syncthreads();

    for (int s = 0; s < tc; s++) {
        int par = s & 1;
        int t = t0 + s;
        int sn = (s + 1 < tc) ? (s + 1) : s;

        // prefetch next gi row into registers
        bf16x8 pg[3];
#pragma unroll
        for (int it = 0; it < 3; it++)
            pg[it] = *(const bf16x8*)(gi + ((size_t)sn * B_ + b0 + bb[it]) * DG_ + dir * G_ + oo[it]);

        // gh = h @ Whh^T
        f32x4 acc[3][2] = {};
        const bf16_t* hcur = &h_lds[par * 4224];
#pragma unroll
        for (int kt = 0; kt < 8; kt++) {
            bf16x8 af = *(const bf16x8*)(hcur + col * 264 + kt * 32 + quad * 8);
#pragma unroll
            for (int g = 0; g < 3; g++)
#pragma unroll
                for (int nt = 0; nt < 2; nt++)
                    acc[g][nt] = __builtin_amdgcn_mfma_f32_16x16x32_bf16(af, wf[g][nt][kt], acc[g][nt], 0, 0, 0);
        }

        // gates + state update (fp32 carry in hold[][])
        bf16_t* hnext = &h_lds[(par ^ 1) * 4224];
        int tp = dir ? (T_ - 1 - t) : t;
#pragma unroll
        for (int nt = 0; nt < 2; nt++) {
            int j = w * 32 + nt * 16 + col;
#pragma unroll
            for (int i = 0; i < 4; i++) {
                int b = quad * 4 + i;
                float gr = acc[0][nt][i] + (float)gi_lds[b * 768 + j]       + brz[0][nt];
                float gz = acc[1][nt][i] + (float)gi_lds[b * 768 + 256 + j] + brz[1][nt];
                float gn = (float)gi_lds[b * 768 + 512 + j] + bin_[nt];
                float r = sigm(gr), z = sigm(gz);
                float n = tanh_(gn + r * (acc[2][nt][i] + bhn[nt]));
                float hv = (1.0f - z) * n + z * hold[nt][i];
                hold[nt][i] = hv;
                hnext[b * 264 + j] = (bf16_t)hv;
                if (y) y[((size_t)tp * B_ + b0 + b) * DH_ + dir * H_ + j] = (bf16_t)hv;
                if (t == T_ - 1) hT[(size_t)(b0 + b) * DH_ + dir * H_ + j] = hv;
            }
        }
        __syncthreads();   // everyone done reading gi_lds(s) and h_lds
        // commit prefetched gi row (single buffer)
#pragma unroll
        for (int it = 0; it < 3; it++)
            *(bf16x8*)(&gi_lds[(it * 512 + tid) * 8]) = pg[it];
        __syncthreads();   // gi_lds(s+1) visible
    }
    // persist h for next chunk
#pragma unroll
    for (int nt = 0; nt < 2; nt++)
#pragma unroll
        for (int i = 0; i < 4; i++) {
            int j = w * 32 + nt * 16 + col;
            hstate[dir * 65536 + (b0 + quad * 4 + i) * 256 + j] = hold[nt][i];
        }
}

// ----------------------------- decoder cell --------------------------------
// h_out = GRUcell(x_src, h_in): gi = x_src@Wx^T + bx (or ov broadcast at t=0),
// gh = h_in@Wh^T + bh. Grid = 16 b-tiles x 8 j-blocks, 256 thr (4 waves x 16 j).
__global__ __launch_bounds__(256) void dec_cell(
    const float* __restrict__ xsrc, const bf16_t* __restrict__ Wx,
    const float* __restrict__ bx, const float* __restrict__ ov,
    const float* __restrict__ hin, const bf16_t* __restrict__ Wh,
    const float* __restrict__ bh, float* __restrict__ hout,
    float* __restrict__ hist) {
    int jblk = blockIdx.x & 7;
    int b0   = (blockIdx.x >> 3) * 16;
    int tid = threadIdx.x, w = tid >> 6, lane = tid & 63, col = lane & 15, quad = lane >> 4;
    int j = jblk * 64 + w * 16 + col;
    bool do_gi = (ov == nullptr);

    f32x4 agi[3] = {}, agh[3] = {};
#pragma unroll 4
    for (int kt = 0; kt < 16; kt++) {
        bf16x8 ah = load_f32x8_as_bf16(hin + (size_t)(b0 + col) * DH_ + kt * 32 + quad * 8);
#pragma unroll
        for (int g = 0; g < 3; g++) {
            bf16x8 bw = *(const bf16x8*)(Wh + (size_t)(g * DH_ + j) * DH_ + kt * 32 + quad * 8);
            agh[g] = __builtin_amdgcn_mfma_f32_16x16x32_bf16(ah, bw, agh[g], 0, 0, 0);
        }
        if (do_gi) {
            bf16x8 ax = load_f32x8_as_bf16(xsrc + (size_t)(b0 + col) * DH_ + kt * 32 + quad * 8);
#pragma unroll
            for (int g = 0; g < 3; g++) {
                bf16x8 bw = *(const bf16x8*)(Wx + (size_t)(g * DH_ + j) * DH_ + kt * 32 + quad * 8);
                agi[g] = __builtin_amdgcn_mfma_f32_16x16x32_bf16(ax, bw, agi[g], 0, 0, 0);
            }
        }
    }
#pragma unroll
    for (int i = 0; i < 4; i++) {
        int b = b0 + quad * 4 + i;
        float gr, gz, gn;
        if (do_gi) {
            gr = agi[0][i] + bx[j];
            gz = agi[1][i] + bx[DH_ + j];
            gn = agi[2][i] + bx[2 * DH_ + j];
        } else {
            gr = ov[j]; gz = ov[DH_ + j]; gn = ov[2 * DH_ + j];
        }
        float hr = agh[0][i] + bh[j];
        float hz = agh[1][i] + bh[DH_ + j];
        float hn = agh[2][i] + bh[2 * DH_ + j];
        float r = sigm(gr + hr), z = sigm(gz + hz);
        float n = tanh_(gn + r * hn);
        float hold = hin[(size_t)b * DH_ + j];
        float hv = (1.0f - z) * n + z * hold;
        hout[(size_t)b * DH_ + j] = hv;
        if (hist) hist[(size_t)b * DH_ + j] = hv;
    }
}

// ------------------------------- FC head -----------------------------------
__global__ __launch_bounds__(256) void fc_all(
    const float* __restrict__ hist, const float* __restrict__ fcw,
    const float* __restrict__ fcb, float* __restrict__ out) {
    int t  = blockIdx.x >> 4;
    int b0 = (blockIdx.x & 15) * 16;
    int tid = threadIdx.x;
    int bl = tid >> 4, o = (tid >> 3) & 1, part = tid & 7;
    const float* hp = hist + ((size_t)t * B_ + b0 + bl) * DH_;
    const float* wp = fcw + o * DH_;
    float s = 0.0f;
    for (int k = part * 64; k < part * 64 + 64; k += 4) {
        f32x4 hv = *(const f32x4*)(hp + k);
        f32x4 wv = *(const f32x4*)(wp + k);
        s += hv[0] * wv[0] + hv[1] * wv[1] + hv[2] * wv[2] + hv[3] * wv[3];
    }
    s += __shfl_down(s, 4); s += __shfl_down(s, 2); s += __shfl_down(s, 1);
    if (part == 0) out[(size_t)(b0 + bl) * (OSL_ * 2) + t * 2 + o] = s + fcb[o];
}

// ------------------------------ launcher -----------------------------------

// fixed workspace offsets (bytes); gi chunk goes last (ws_size-adaptive)
#define OFF_WIH0E 0ull
#define OFF_WHH0E 196608ull
#define OFF_WIH1E 983040ull
#define OFF_WHH1E 2555904ull
#define OFF_WDHH0 3342336ull
#define OFF_WDIH1 4915200ull
#define OFF_WDHH1 6488064ull
#define OFF_WEFF  8060928ull
#define OFF_BEFF  9633792ull
#define OFF_OV    9658368ull
#define OFF_H0A   9682944ull
#define OFF_H0B   10207232ull
#define OFF_H1A   10731520ull
#define OFF_H1B   11255808ull
#define OFF_HST   11780096ull
#define OFF_HIST  12304384ull
#define OFF_XCAT  22790144ull
#define OFF_GI    157007872ull

extern "C" void kernel_launch(void* const* d_in, const int* in_sizes, int n_in,
                              void* d_out, int out_size, void* d_ws, size_t ws_size,
                              hipStream_t stream) {
    const float* x      = (const float*)d_in[0];
    const float* st     = (const float*)d_in[1];
    const float* eWih0  = (const float*)d_in[2];
    const float* eWhh0  = (const float*)d_in[3];
    const float* ebih0  = (const float*)d_in[4];
    const float* ebhh0  = (const float*)d_in[5];
    const float* eWih1  = (const float*)d_in[6];
    const float* eWhh1  = (const float*)d_in[7];
    const float* ebih1  = (const float*)d_in[8];
    const float* ebhh1  = (const float*)d_in[9];
    const float* dWih0  = (const float*)d_in[10];
    const float* dWhh0  = (const float*)d_in[11];
    const float* dbih0  = (const float*)d_in[12];
    const float* dbhh0  = (const float*)d_in[13];
    const float* dWih1  = (const float*)d_in[14];
    const float* dWhh1  = (const float*)d_in[15];
    const float* dbih1  = (const float*)d_in[16];
    const float* dbhh1  = (const float*)d_in[17];
    const float* fcW    = (const float*)d_in[18];
    const float* fcb    = (const float*)d_in[19];

    char* ws = (char*)d_ws;
    bf16_t* wih0e = (bf16_t*)(ws + OFF_WIH0E);
    bf16_t* whh0e = (bf16_t*)(ws + OFF_WHH0E);
    bf16_t* wih1e = (bf16_t*)(ws + OFF_WIH1E);
    bf16_t* whh1e = (bf16_t*)(ws + OFF_WHH1E);
    bf16_t* wdhh0 = (bf16_t*)(ws + OFF_WDHH0);
    bf16_t* wdih1 = (bf16_t*)(ws + OFF_WDIH1);
    bf16_t* wdhh1 = (bf16_t*)(ws + OFF_WDHH1);
    bf16_t* weff  = (bf16_t*)(ws + OFF_WEFF);
    float*  beff  = (float*)(ws + OFF_BEFF);
    float*  ovp   = (float*)(ws + OFF_OV);
    float*  h0buf[2] = { (float*)(ws + OFF_H0A), (float*)(ws + OFF_H0B) };
    float*  h1buf[2] = { (float*)(ws + OFF_H1A), (float*)(ws + OFF_H1B) };
    float*  hstate = (float*)(ws + OFF_HST);
    float*  hist  = (float*)(ws + OFF_HIST);
    bf16_t* xcat  = (bf16_t*)(ws + OFF_XCAT);
    bf16_t* gi    = (bf16_t*)(ws + OFF_GI);

    // pick largest chunk length that fits the workspace
    int Tc = 512;
    while (Tc > 8 && OFF_GI + (unsigned long long)Tc * 786432ull > (unsigned long long)ws_size)
        Tc >>= 1;
    int nch = T_ / Tc;

    // --- prep ---
    cast_f32_bf16<<<(2*G_*F_ + 255)/256, 256, 0, stream>>>(eWih0, wih0e, 2*G_*F_);
    cast_f32_bf16<<<(2*G_*H_ + 255)/256, 256, 0, stream>>>(eWhh0, whh0e, 2*G_*H_);
    cast_f32_bf16<<<(2*G_*DH_ + 255)/256, 256, 0, stream>>>(eWih1, wih1e, 2*G_*DH_);
    cast_f32_bf16<<<(2*G_*H_ + 255)/256, 256, 0, stream>>>(eWhh1, whh1e, 2*G_*H_);
    cast_f32_bf16<<<(DG_*DH_ + 255)/256, 256, 0, stream>>>(dWhh0, wdhh0, DG_*DH_);
    cast_f32_bf16<<<(DG_*DH_ + 255)/256, 256, 0, stream>>>(dWih1, wdih1, DG_*DH_);
    cast_f32_bf16<<<(DG_*DH_ + 255)/256, 256, 0, stream>>>(dWhh1, wdhh1, DG_*DH_);
    weff_prep<<<(DG_*DH_ + 255)/256, 256, 0, stream>>>(dWih0, fcW, fcb, dbih0, st, weff, beff, ovp);

    // --- encoder layer 0 (gi from x, K=64) ---
    for (int c = 0; c < nch; c++) {
        gemm_gi<<<dim3(Tc * 2, 12), 256, 0, stream>>>(x, nullptr, wih0e, gi, c * Tc, 64);
        gru_scan<<<32, 512, 0, stream>>>(gi, c * Tc, Tc, whh0e, ebih0, ebhh0, hstate, xcat, h0buf[0]);
    }
    // --- encoder layer 1 (gi from xcat, K=512) ---
    for (int c = 0; c < nch; c++) {
        gemm_gi<<<dim3(Tc * 2, 12), 256, 0, stream>>>(nullptr, xcat, wih1e, gi, c * Tc, 512);
        gru_scan<<<32, 512, 0, stream>>>(gi, c * Tc, Tc, whh1e, ebih1, ebhh1, hstate, nullptr, h1buf[0]);
    }

    // --- decoder ---
    int p0 = 0, p1 = 0;
    for (int t = 0; t < OSL_; t++) {
        dec_cell<<<128, 256, 0, stream>>>(h1buf[p1], weff, beff, (t == 0 ? ovp : nullptr),
                                          h0buf[p0], wdhh0, dbhh0, h0buf[p0 ^ 1], nullptr);
        p0 ^= 1;
        dec_cell<<<128, 256, 0, stream>>>(h0buf[p0], wdih1, dbih1, nullptr,
                                          h1buf[p1], wdhh1, dbhh1, h1buf[p1 ^ 1],
                                          hist + (size_t)t * B_ * DH_);
        p1 ^= 1;
    }
    fc_all<<<OSL_ * 16, 256, 0, stream>>>(hist, fcW, fcb, (float*)d_out);
}